// Round 1
// baseline (290.614 us; speedup 1.0000x reference)
//
#include <hip/hip_runtime.h>

#define MAXB 1024

// Per-graph start offsets (reference: counts -> cumsum). One block.
__global__ void offsets_k(const int* __restrict__ bv, int N,
                          const int* __restrict__ eb, int E,
                          const int* __restrict__ nG,
                          int* __restrict__ node_off, int* __restrict__ e_off) {
    __shared__ int c1[MAXB];
    __shared__ int c2[MAXB];
    int B = nG[0];
    if (B > MAXB) B = MAXB;
    for (int i = threadIdx.x; i < B; i += blockDim.x) { c1[i] = 0; c2[i] = 0; }
    __syncthreads();
    for (int i = threadIdx.x; i < N; i += blockDim.x) atomicAdd(&c1[bv[i]], 1);
    for (int i = threadIdx.x; i < E; i += blockDim.x) atomicAdd(&c2[eb[i]], 1);
    __syncthreads();
    if (threadIdx.x == 0) {
        int a = 0, b = 0;
        for (int g = 0; g < B; ++g) {
            node_off[g] = a; a += c1[g];
            e_off[g]    = b; b += c2[g];
        }
    }
}

__global__ void x2_copy_k(const float4* __restrict__ x, float4* __restrict__ x2, int n4) {
    int t = blockIdx.x * blockDim.x + threadIdx.x;
    if (t < n4) x2[t] = x[t];
}

// x2 += segment_sum(edge_attr, dst)
__global__ void x2_add_k(const float* __restrict__ edge_attr,
                         const int* __restrict__ edge_index,
                         int E, int emb, float* __restrict__ x2) {
    int t = blockIdx.x * blockDim.x + threadIdx.x;
    if (t >= E * emb) return;
    int e = t / emb;
    int c = t - e * emb;
    int dst = edge_index[E + e];  // row 1 of (2,E)
    atomicAdd(&x2[dst * emb + c], edge_attr[t]);
}

// Default pattern for BOTH output regions: diag -> W[1], else -> W[2].
// (Edge cells are overwritten afterwards; their mask row is 0 anyway.)
__global__ void fill_k(float4* __restrict__ out, unsigned int total4,
                       const float4* __restrict__ encW,
                       const float4* __restrict__ e2eW,
                       const int* __restrict__ nG,
                       int N, int E, int emb4) {
    int B = nG[0];
    unsigned int n  = (unsigned int)(N / B);
    unsigned int Eg = (unsigned int)(E / B);
    unsigned int uemb4 = (unsigned int)emb4;
    unsigned int edge4 = (unsigned int)N * n * uemb4;   // floats4 in edge_dense region
    unsigned int stride = gridDim.x * blockDim.x;
    for (unsigned int idx = blockIdx.x * blockDim.x + threadIdx.x; idx < total4; idx += stride) {
        unsigned int r = idx;
        const float4* W = encW;
        unsigned int dim = n;
        if (r >= edge4) { r -= edge4; W = e2eW; dim = Eg; }
        unsigned int cell = r / uemb4;
        unsigned int c4 = r - cell * uemb4;
        unsigned int j = cell % dim;
        unsigned int i = (cell / dim) % dim;
        out[idx] = (i == j) ? W[uemb4 + c4] : W[2u * uemb4 + c4];
    }
}

// Overwrite the E edge cells: ea = edge_attr + x[src] + x[dst]
__global__ void scatter_edge_k(const float4* __restrict__ edge_attr,
                               const float4* __restrict__ x,
                               const int* __restrict__ edge_index,
                               const int* __restrict__ bv,
                               const int* __restrict__ node_off,
                               const float4* __restrict__ encW,
                               const int* __restrict__ nG,
                               int N, int E, int emb4,
                               float4* __restrict__ out) {
    int t = blockIdx.x * blockDim.x + threadIdx.x;
    if (t >= E * emb4) return;
    int e = t / emb4;
    int c4 = t - e * emb4;
    int src = edge_index[e];
    int dst = edge_index[E + e];
    int g = bv[src];
    int B = nG[0];
    int n = N / B;
    int li = src - node_off[g];
    int lj = dst - node_off[g];
    float4 a  = edge_attr[t];
    float4 xs = x[(long)src * emb4 + c4];
    float4 xd = x[(long)dst * emb4 + c4];
    float4 v;
    v.x = a.x + xs.x + xd.x;
    v.y = a.y + xs.y + xd.y;
    v.z = a.z + xs.z + xd.z;
    v.w = a.w + xs.w + xd.w;
    if (li == lj) {  // adj==3 -> index -1 wraps to masked row 2 in the reference
        float4 wv = encW[2 * emb4 + c4];
        v.x += wv.x; v.y += wv.y; v.z += wv.z; v.w += wv.w;
    }
    long addr = ((long)(g * n + li) * n + lj) * emb4 + c4;
    out[addr] = v;
}

// Overwrite the E2 e2e cells: x2[e2e_node_index[f]]
__global__ void scatter_e2e_k(const float* __restrict__ x2f,
                              const int* __restrict__ e2e_ei,
                              const int* __restrict__ eb,
                              const int* __restrict__ e_off,
                              const int* __restrict__ e2e_nidx,
                              const float4* __restrict__ e2eW,
                              const int* __restrict__ nG,
                              int N, int E, int E2, int emb4,
                              float4* __restrict__ out) {
    int t = blockIdx.x * blockDim.x + threadIdx.x;
    if (t >= E2 * emb4) return;
    int f = t / emb4;
    int c4 = t - f * emb4;
    int es = e2e_ei[f];
    int ed = e2e_ei[E2 + f];
    int g = eb[es];
    int B = nG[0];
    int n = N / B;
    int Eg = E / B;
    int eli = es - e_off[g];
    int elj = ed - e_off[g];
    const float4* x2 = (const float4*)x2f;
    float4 v = x2[(long)e2e_nidx[f] * emb4 + c4];
    if (eli == elj) {
        float4 wv = e2eW[2 * emb4 + c4];
        v.x += wv.x; v.y += wv.y; v.z += wv.z; v.w += wv.w;
    }
    long edge4 = (long)N * n * emb4;  // edge_dense region size in float4s
    long addr = edge4 + ((long)(g * Eg + eli) * Eg + elj) * emb4 + c4;
    out[addr] = v;
}

extern "C" void kernel_launch(void* const* d_in, const int* in_sizes, int n_in,
                              void* d_out, int out_size, void* d_ws, size_t ws_size,
                              hipStream_t stream) {
    const float* x          = (const float*)d_in[0];
    const float* edge_attr  = (const float*)d_in[1];
    const float* enc_W      = (const float*)d_in[2];
    const float* e2e_W      = (const float*)d_in[3];
    const int* edge_index   = (const int*)d_in[4];
    const int* batch_vec    = (const int*)d_in[5];
    const int* e2e_ei       = (const int*)d_in[6];
    const int* e_batch      = (const int*)d_in[7];
    const int* e2e_nidx     = (const int*)d_in[8];
    const int* nG           = (const int*)d_in[9];

    int emb  = in_sizes[2] / 3;        // enc_W is (3, emb)
    int emb4 = emb / 4;
    int N    = in_sizes[0] / emb;      // x is (N, emb)
    int E    = in_sizes[1] / emb;      // edge_attr is (E, emb)
    int E2   = in_sizes[8];            // e2e_node_index is (E2,)

    char* ws      = (char*)d_ws;
    int* node_off = (int*)ws;               // up to MAXB ints
    int* e_off    = (int*)(ws + 4096);      // up to MAXB ints
    float* x2     = (float*)(ws + 8192);    // N*emb floats

    offsets_k<<<1, 256, 0, stream>>>(batch_vec, N, e_batch, E, nG, node_off, e_off);

    int n4x = (N * emb) / 4;
    x2_copy_k<<<(n4x + 255) / 256, 256, 0, stream>>>((const float4*)x, (float4*)x2, n4x);

    int tadd = E * emb;
    x2_add_k<<<(tadd + 255) / 256, 256, 0, stream>>>(edge_attr, edge_index, E, emb, x2);

    unsigned int total4 = (unsigned int)(out_size / 4);
    fill_k<<<8192, 256, 0, stream>>>((float4*)d_out, total4,
                                     (const float4*)enc_W, (const float4*)e2e_W,
                                     nG, N, E, emb4);

    int t1 = E * emb4;
    scatter_edge_k<<<(t1 + 255) / 256, 256, 0, stream>>>(
        (const float4*)edge_attr, (const float4*)x, edge_index, batch_vec,
        node_off, (const float4*)enc_W, nG, N, E, emb4, (float4*)d_out);

    int t2 = E2 * emb4;
    scatter_e2e_k<<<(t2 + 255) / 256, 256, 0, stream>>>(
        x2, e2e_ei, e_batch, e_off, e2e_nidx,
        (const float4*)e2e_W, nG, N, E, E2, emb4, (float4*)d_out);
}